// Round 1
// baseline (253.861 us; speedup 1.0000x reference)
//
#include <hip/hip_runtime.h>
#include <cstdint>
#include <cstddef>

typedef unsigned short u16;
typedef unsigned int   u32;
using short8 = __attribute__((ext_vector_type(8))) short;
using f32x4  = __attribute__((ext_vector_type(4))) float;

// B=8, N=8192, H=256, A=64 (F=320), S=32
#define NB    8
#define NN    8192
#define HH    256
#define FF    320
#define SS    32
#define NROWS 65536          // B*N
#define NCHUNK 64            // K-split chunks for pooling GEMM (8192/128)

__device__ __forceinline__ u16 f2bf(float f) {
    union { float f; u32 u; } v; v.f = f;
    u32 r = v.u + 0x7fffu + ((v.u >> 16) & 1u);   // RNE
    return (u16)(r >> 16);
}

// ---------------- prep: cast Wi,Wj (fp32 [256][320]) to bf16, concatenated ----------------
__global__ __launch_bounds__(256) void prep_w(const float* __restrict__ Wi,
                                              const float* __restrict__ Wj,
                                              u16* __restrict__ Wb) {
    int idx = blockIdx.x * 256 + threadIdx.x;       // 0..163839
    float v = (idx < 81920) ? Wi[idx] : Wj[idx - 81920];
    Wb[idx] = f2bf(v);
}

// ---------------- kernel 1: x@Wi^T, x@Wj^T -> gate -> x_all (bf16, transposed [b][h][n]) + norm^2 ----------------
// Block tile: 128 rows (n) x 64 h (both matrices => 128 accumulator cols). BK=64, K=320 (5 iters).
__global__ __launch_bounds__(256) void gemm_gate(
    const float* __restrict__ x, const u16* __restrict__ Wb,
    const float* __restrict__ bi, const float* __restrict__ bj,
    u16* __restrict__ xa, float* __restrict__ normsq)
{
    __shared__ u16 lA[128 * 72];      // [row][k] stride 72 shorts (144 B, 16B-mult, pad vs conflicts)
    __shared__ u16 lB[2 * 64 * 64];   // [mat][n][k-groups XOR-swizzled], no pad (global_load_lds)

    const int bx = blockIdx.x;
    const int ht = bx & 3;            // h-tile: h0 = ht*64
    const int mb = bx >> 2;           // row-tile 0..511
    const int m0 = mb * 128;
    const int h0 = ht * 64;
    const int b_idx = m0 >> 13;
    const int n0 = m0 & 8191;

    const int tid  = threadIdx.x;
    const int w    = tid >> 6;
    const int lane = tid & 63;
    const int quad = lane >> 4;
    const int l15  = lane & 15;

    f32x4 acc[2][2][4];               // [mat][mt][nt]
    #pragma unroll
    for (int a = 0; a < 2; ++a)
        #pragma unroll
        for (int b = 0; b < 2; ++b)
            #pragma unroll
            for (int c = 0; c < 4; ++c)
                acc[a][b][c] = (f32x4){0.f, 0.f, 0.f, 0.f};

    for (int kt = 0; kt < 5; ++kt) {
        const int f0 = kt * 64;
        if (kt) __syncthreads();
        // ---- stage A: 128x64 fp32 -> bf16 (manual; 8 float4 per thread) ----
        #pragma unroll
        for (int i = 0; i < 8; ++i) {
            int c   = i * 256 + tid;            // 0..2047
            int row = c >> 4;
            int fq  = (c & 15) * 4;
            const float4 v = *reinterpret_cast<const float4*>(
                &x[(size_t)(m0 + row) * FF + f0 + fq]);
            uint2 pk;
            pk.x = (u32)f2bf(v.x) | ((u32)f2bf(v.y) << 16);
            pk.y = (u32)f2bf(v.z) | ((u32)f2bf(v.w) << 16);
            *reinterpret_cast<uint2*>(&lA[row * 72 + fq]) = pk;
        }
        // ---- stage B: 2 matrices x 64 h x 64 k via global_load_lds width 16, XOR k-group swizzle ----
        #pragma unroll
        for (int j = 0; j < 4; ++j) {
            int slot = w * 4 + j;               // 0..15, wave-uniform
            int mat  = slot >> 3;
            int nb   = (slot & 7) * 8;
            int nl   = nb + (lane >> 3);
            int g    = (lane & 7) ^ ((lane >> 3) & 7);
            const u16* gsrc = Wb + mat * 81920 + (size_t)(h0 + nl) * FF + f0 + g * 8;
            u16* ldst = &lB[mat * 4096 + nb * 64];   // wave-uniform base; HW adds lane*16
            __builtin_amdgcn_global_load_lds(
                (const __attribute__((address_space(1))) void*)gsrc,
                (__attribute__((address_space(3))) void*)ldst, 16, 0, 0);
        }
        __syncthreads();
        // ---- MFMA: per wave 2 mt x 4 nt x 2 mat per kk ----
        #pragma unroll
        for (int kk = 0; kk < 2; ++kk) {
            short8 af[2];
            #pragma unroll
            for (int mt = 0; mt < 2; ++mt) {
                int row = w * 32 + mt * 16 + l15;
                af[mt] = *reinterpret_cast<const short8*>(&lA[row * 72 + kk * 32 + quad * 8]);
            }
            #pragma unroll
            for (int mat = 0; mat < 2; ++mat) {
                #pragma unroll
                for (int nt = 0; nt < 4; ++nt) {
                    int n = nt * 16 + l15;
                    int p = (kk * 4 + quad) ^ (n & 7);
                    short8 bv = *reinterpret_cast<const short8*>(&lB[mat * 4096 + n * 64 + p * 8]);
                    #pragma unroll
                    for (int mt = 0; mt < 2; ++mt)
                        acc[mat][mt][nt] = __builtin_amdgcn_mfma_f32_16x16x32_bf16(
                            af[mt], bv, acc[mat][mt][nt], 0, 0, 0);
                }
            }
        }
    }

    // ---- epilogue: bias, gate, store x_all^T bf16, norm^2 ----
    float bi_v[4], bj_v[4];
    #pragma unroll
    for (int nt = 0; nt < 4; ++nt) {
        int h = h0 + nt * 16 + l15;
        bi_v[nt] = bi[h];
        bj_v[nt] = bj[h];
    }
    float s0[2][4];
    #pragma unroll
    for (int mt = 0; mt < 2; ++mt)
        #pragma unroll
        for (int r = 0; r < 4; ++r) s0[mt][r] = 0.f;

    #pragma unroll
    for (int mt = 0; mt < 2; ++mt) {
        #pragma unroll
        for (int nt = 0; nt < 4; ++nt) {
            int h = h0 + nt * 16 + l15;
            float xall[4];
            #pragma unroll
            for (int r = 0; r < 4; ++r) {
                float yi = acc[0][mt][nt][r] + bi_v[nt];
                float yj = acc[1][mt][nt][r] + bj_v[nt];
                float sg = 1.f / (1.f + __expf(-yi));
                float e2 = __expf(-2.f * yj);
                float th = (1.f - e2) / (1.f + e2);
                float xv = sg * th;
                xall[r] = xv;
                s0[mt][r] += xv * xv;
            }
            uint2 pk;
            pk.x = (u32)f2bf(xall[0]) | ((u32)f2bf(xall[1]) << 16);
            pk.y = (u32)f2bf(xall[2]) | ((u32)f2bf(xall[3]) << 16);
            size_t o = (size_t)b_idx * ((size_t)HH * NN) + (size_t)h * NN
                     + (size_t)(n0 + w * 32 + mt * 16 + quad * 4);
            *reinterpret_cast<uint2*>(&xa[o]) = pk;   // 4 consecutive n, 8B store
        }
    }
    // reduce norm^2 across the 16 lanes of each quad (rows = quad*4+r)
    #pragma unroll
    for (int m = 1; m <= 8; m <<= 1) {
        #pragma unroll
        for (int mt = 0; mt < 2; ++mt)
            #pragma unroll
            for (int r = 0; r < 4; ++r)
                s0[mt][r] += __shfl_xor(s0[mt][r], m, 64);
    }
    if (l15 == 0) {
        #pragma unroll
        for (int mt = 0; mt < 2; ++mt)
            #pragma unroll
            for (int r = 0; r < 4; ++r)
                atomicAdd(&normsq[m0 + w * 32 + mt * 16 + quad * 4 + r], s0[mt][r]);
    }
}

// ---------------- kernel 2: masked softmax over N per (b,s); weight -> out1 fp32 ----------------
__global__ __launch_bounds__(256) void softmax_k(
    const float* __restrict__ nm, const float* __restrict__ normsq,
    float* __restrict__ out1)
{
    __shared__ float red[4];
    int bs = blockIdx.x;                 // 0..255
    int b  = bs >> 5;
    const float* src = nm + (size_t)bs * NN;
    float* dst       = out1 + (size_t)bs * NN;
    const float* ns  = normsq + (size_t)b * NN;
    int tid = threadIdx.x;
    float e[32];
    float sum = 0.f;
    #pragma unroll
    for (int i = 0; i < 32; ++i) {
        int n = i * 256 + tid;
        float logit = src[n] * sqrtf(ns[n]);
        float v = (logit > 0.f) ? __expf(logit) : 0.f;
        e[i] = v;
        sum += v;
    }
    #pragma unroll
    for (int m = 1; m <= 32; m <<= 1) sum += __shfl_xor(sum, m, 64);
    int w = tid >> 6, lane = tid & 63;
    if (lane == 0) red[w] = sum;
    __syncthreads();
    float part = red[0] + red[1] + red[2] + red[3];
    float inv  = (part > 0.f) ? (1.f / part) : 0.f;
    #pragma unroll
    for (int i = 0; i < 32; ++i) dst[i * 256 + tid] = e[i] * inv;
}

// ---------------- kernel 3: pooling GEMM partials. C[h][s] += xa_t[h][n] * w[s][n] over n-chunk ----------------
__global__ __launch_bounds__(256) void pooled_k(
    const u16* __restrict__ xa, const float* __restrict__ wgt,
    float* __restrict__ part)
{
    __shared__ u16 lw[32 * 136];         // [s][k] stride 136 shorts (272 B)
    int bx = blockIdx.x;                 // 512
    int b  = bx >> 6, c = bx & 63;       // n-chunk of 128
    int tid = threadIdx.x, w = tid >> 6, lane = tid & 63, quad = lane >> 4, l15 = lane & 15;

    // stage weights fp32 -> bf16 (32 s x 128 n)
    {
        int s  = tid >> 3;
        int jq = (tid & 7) * 16;
        const float* src = wgt + (size_t)(b * SS + s) * NN + c * 128 + jq;
        #pragma unroll
        for (int q = 0; q < 4; ++q) {
            float4 v = *reinterpret_cast<const float4*>(src + q * 4);
            uint2 pk;
            pk.x = (u32)f2bf(v.x) | ((u32)f2bf(v.y) << 16);
            pk.y = (u32)f2bf(v.z) | ((u32)f2bf(v.w) << 16);
            *reinterpret_cast<uint2*>(&lw[s * 136 + jq + q * 4]) = pk;
        }
    }
    __syncthreads();

    f32x4 acc[4][2];
    #pragma unroll
    for (int a = 0; a < 4; ++a)
        #pragma unroll
        for (int s = 0; s < 2; ++s) acc[a][s] = (f32x4){0.f, 0.f, 0.f, 0.f};

    const u16* abase = xa + (size_t)b * ((size_t)HH * NN) + c * 128;
    #pragma unroll
    for (int kk = 0; kk < 4; ++kk) {
        short8 av[4];
        #pragma unroll
        for (int htl = 0; htl < 4; ++htl) {
            int h = w * 64 + htl * 16 + l15;
            av[htl] = *reinterpret_cast<const short8*>(abase + (size_t)h * NN + kk * 32 + quad * 8);
        }
        #pragma unroll
        for (int st = 0; st < 2; ++st) {
            int s = st * 16 + l15;
            short8 bv = *reinterpret_cast<const short8*>(&lw[s * 136 + kk * 32 + quad * 8]);
            #pragma unroll
            for (int htl = 0; htl < 4; ++htl)
                acc[htl][st] = __builtin_amdgcn_mfma_f32_16x16x32_bf16(av[htl], bv, acc[htl][st], 0, 0, 0);
        }
    }
    float* pb = part + (size_t)(b * NCHUNK + c) * 8192;   // [s*256 + h]
    #pragma unroll
    for (int htl = 0; htl < 4; ++htl) {
        #pragma unroll
        for (int st = 0; st < 2; ++st) {
            int h = w * 64 + htl * 16 + quad * 4;
            int s = st * 16 + l15;
            *reinterpret_cast<f32x4*>(&pb[s * 256 + h]) = acc[htl][st];
        }
    }
}

// ---------------- kernel 4: reduce partials over chunks + tanh -> out0 ----------------
__global__ __launch_bounds__(256) void reduce_tanh(const float* __restrict__ part,
                                                   float* __restrict__ out0)
{
    int gid = blockIdx.x * 256 + threadIdx.x;   // 0..65535 = b*8192 + s*256 + h
    int b = gid >> 13, r = gid & 8191;
    const float* p = part + (size_t)b * NCHUNK * 8192 + r;
    float s = 0.f;
    #pragma unroll
    for (int c = 0; c < NCHUNK; ++c) s += p[(size_t)c * 8192];
    out0[gid] = tanhf(s);
}

extern "C" void kernel_launch(void* const* d_in, const int* in_sizes, int n_in,
                              void* d_out, int out_size, void* d_ws, size_t ws_size,
                              hipStream_t stream) {
    const float* x  = (const float*)d_in[0];
    const float* nm = (const float*)d_in[1];
    const float* Wi = (const float*)d_in[2];
    const float* bi = (const float*)d_in[3];
    const float* Wj = (const float*)d_in[4];
    const float* bj = (const float*)d_in[5];
    float* out0 = (float*)d_out;
    float* out1 = out0 + NB * SS * HH;           // 65536

    char* ws = (char*)d_ws;
    u16*   Wb     = (u16*)ws;                                    // 327,680 B
    u16*   xa     = (u16*)(ws + 327680);                         // 33,554,432 B
    float* normsq = (float*)(ws + 327680 + 33554432);            // 262,144 B
    float* part   = (float*)(ws + 327680 + 33554432 + 262144);   // 16,777,216 B

    hipMemsetAsync(normsq, 0, NROWS * sizeof(float), stream);
    prep_w     <<<640,  256, 0, stream>>>(Wi, Wj, Wb);
    gemm_gate  <<<2048, 256, 0, stream>>>(x, Wb, bi, bj, xa, normsq);
    softmax_k  <<<256,  256, 0, stream>>>(nm, normsq, out1);
    pooled_k   <<<512,  256, 0, stream>>>(xa, out1, part);
    reduce_tanh<<<256,  256, 0, stream>>>(part, out0);
}

// Round 2
// 232.028 us; speedup vs baseline: 1.0941x; 1.0941x over previous
//
#include <hip/hip_runtime.h>
#include <cstdint>
#include <cstddef>

typedef unsigned short u16;
typedef unsigned int   u32;
using short8 = __attribute__((ext_vector_type(8))) short;
using f32x4  = __attribute__((ext_vector_type(4))) float;

// B=8, N=8192, H=256, A=64 (F=320), S=32
#define NB    8
#define NN    8192
#define HH    256
#define FF    320
#define SS    32
#define NROWS 65536

__device__ __forceinline__ u16 f2bf(float f) {
    union { float f; u32 u; } v; v.f = f;
    u32 r = v.u + 0x7fffu + ((v.u >> 16) & 1u);   // RNE
    return (u16)(r >> 16);
}

// ---------------- prep: cast Wi,Wj (fp32 [256][320]) to bf16, concatenated ----------------
__global__ __launch_bounds__(256) void prep_w(const float* __restrict__ Wi,
                                              const float* __restrict__ Wj,
                                              u16* __restrict__ Wb) {
    int idx = blockIdx.x * 256 + threadIdx.x;       // 0..163839
    float v = (idx < 81920) ? Wi[idx] : Wj[idx - 81920];
    Wb[idx] = f2bf(v);
}

// ---------------- kernel 1: x@Wi^T, x@Wj^T -> gate -> x_all (bf16 [b][h][n]) + norm^2 ----------------
// Block: 128 rows x 64 h (x2 matrices = 128 acc cols). BK=64, 5 iters.
// Double-buffered LDS, ONE barrier per iter; A reg-prefetch + cast at tail; B via global_load_lds w=16.
__global__ __launch_bounds__(256, 2) void gemm_gate(
    const float* __restrict__ x, const u16* __restrict__ Wb,
    const float* __restrict__ bi, const float* __restrict__ bj,
    u16* __restrict__ xa, float* __restrict__ normsq)
{
    __shared__ u16 lA[2][128 * 72];   // [buf][row][k] stride 72 shorts (144 B)
    __shared__ u16 lB[2][8192];       // [buf][mat*4096 + n*64 + swizzled k-group*8]

    const int bx = blockIdx.x;
    const int ht = bx & 3;            // h-tile: h0 = ht*64
    const int mb = bx >> 2;           // row-tile 0..511
    const int m0 = mb * 128;
    const int h0 = ht * 64;
    const int b_idx = m0 >> 13;
    const int n0 = m0 & 8191;

    const int tid  = threadIdx.x;
    const int w    = tid >> 6;
    const int lane = tid & 63;
    const int quad = lane >> 4;
    const int l15  = lane & 15;

    // A-prefetch addressing: thread covers 8 float4 chunks of the 128x64 fp32 tile
    int a_row[8], a_fq[8];
    #pragma unroll
    for (int i = 0; i < 8; ++i) {
        int c = i * 256 + tid;        // 0..2047
        a_row[i] = c >> 4;
        a_fq[i]  = (c & 15) * 4;
    }

    // B staging addressing (wave-uniform dest + lane*16)
    const int nl_b = (lane >> 3);
    const int g_b  = (lane & 7) ^ ((lane >> 3) & 7);

    f32x4 acc[2][2][4];
    #pragma unroll
    for (int a = 0; a < 2; ++a)
        #pragma unroll
        for (int b = 0; b < 2; ++b)
            #pragma unroll
            for (int c = 0; c < 4; ++c)
                acc[a][b][c] = (f32x4){0.f, 0.f, 0.f, 0.f};

    float4 pre[8];

    // ---- prologue: iter 0 into buf 0 ----
    #pragma unroll
    for (int i = 0; i < 8; ++i)
        pre[i] = *reinterpret_cast<const float4*>(&x[(size_t)(m0 + a_row[i]) * FF + a_fq[i]]);
    #pragma unroll
    for (int j = 0; j < 4; ++j) {
        int slot = w * 4 + j;
        int mat  = slot >> 3;
        int nb   = (slot & 7) * 8;
        const u16* gsrc = Wb + mat * 81920 + (size_t)(h0 + nb + nl_b) * FF + g_b * 8;
        u16* ldst = &lB[0][mat * 4096 + nb * 64];
        __builtin_amdgcn_global_load_lds(
            (const __attribute__((address_space(1))) void*)gsrc,
            (__attribute__((address_space(3))) void*)ldst, 16, 0, 0);
    }
    #pragma unroll
    for (int i = 0; i < 8; ++i) {
        uint2 pk;
        pk.x = (u32)f2bf(pre[i].x) | ((u32)f2bf(pre[i].y) << 16);
        pk.y = (u32)f2bf(pre[i].z) | ((u32)f2bf(pre[i].w) << 16);
        *reinterpret_cast<uint2*>(&lA[0][a_row[i] * 72 + a_fq[i]]) = pk;
    }

    for (int kt = 0; kt < 5; ++kt) {
        const int cur = kt & 1;
        const int nxt = cur ^ 1;
        __syncthreads();              // drains vmcnt+lgkm: buf[cur] ready, buf[nxt] free

        if (kt < 4) {
            const int f1 = (kt + 1) * 64;
            // issue B loads for next iter (direct to LDS)
            #pragma unroll
            for (int j = 0; j < 4; ++j) {
                int slot = w * 4 + j;
                int mat  = slot >> 3;
                int nb   = (slot & 7) * 8;
                const u16* gsrc = Wb + mat * 81920 + (size_t)(h0 + nb + nl_b) * FF + f1 + g_b * 8;
                u16* ldst = &lB[nxt][mat * 4096 + nb * 64];
                __builtin_amdgcn_global_load_lds(
                    (const __attribute__((address_space(1))) void*)gsrc,
                    (__attribute__((address_space(3))) void*)ldst, 16, 0, 0);
            }
            // issue A loads for next iter into registers
            #pragma unroll
            for (int i = 0; i < 8; ++i)
                pre[i] = *reinterpret_cast<const float4*>(
                    &x[(size_t)(m0 + a_row[i]) * FF + f1 + a_fq[i]]);
        }

        // ---- compute from buf[cur] ----
        #pragma unroll
        for (int kk = 0; kk < 2; ++kk) {
            short8 af[2];
            #pragma unroll
            for (int mt = 0; mt < 2; ++mt) {
                int row = w * 32 + mt * 16 + l15;
                af[mt] = *reinterpret_cast<const short8*>(&lA[cur][row * 72 + kk * 32 + quad * 8]);
            }
            #pragma unroll
            for (int mat = 0; mat < 2; ++mat) {
                #pragma unroll
                for (int nt = 0; nt < 4; ++nt) {
                    int n = nt * 16 + l15;
                    int p = (kk * 4 + quad) ^ (n & 7);
                    short8 bv = *reinterpret_cast<const short8*>(&lB[cur][mat * 4096 + n * 64 + p * 8]);
                    #pragma unroll
                    for (int mt = 0; mt < 2; ++mt)
                        acc[mat][mt][nt] = __builtin_amdgcn_mfma_f32_16x16x32_bf16(
                            af[mt], bv, acc[mat][mt][nt], 0, 0, 0);
                }
            }
        }

        if (kt < 4) {
            // cast prefetched A and write to buf[nxt] (barrier of next iter makes it visible)
            #pragma unroll
            for (int i = 0; i < 8; ++i) {
                uint2 pk;
                pk.x = (u32)f2bf(pre[i].x) | ((u32)f2bf(pre[i].y) << 16);
                pk.y = (u32)f2bf(pre[i].z) | ((u32)f2bf(pre[i].w) << 16);
                *reinterpret_cast<uint2*>(&lA[nxt][a_row[i] * 72 + a_fq[i]]) = pk;
            }
        }
    }

    // ---- epilogue: bias, gate, store x_all^T bf16, norm^2 ----
    float bi_v[4], bj_v[4];
    #pragma unroll
    for (int nt = 0; nt < 4; ++nt) {
        int h = h0 + nt * 16 + l15;
        bi_v[nt] = bi[h];
        bj_v[nt] = bj[h];
    }
    float s0[2][4];
    #pragma unroll
    for (int mt = 0; mt < 2; ++mt)
        #pragma unroll
        for (int r = 0; r < 4; ++r) s0[mt][r] = 0.f;

    #pragma unroll
    for (int mt = 0; mt < 2; ++mt) {
        #pragma unroll
        for (int nt = 0; nt < 4; ++nt) {
            int h = h0 + nt * 16 + l15;
            float xall[4];
            #pragma unroll
            for (int r = 0; r < 4; ++r) {
                float yi = acc[0][mt][nt][r] + bi_v[nt];
                float yj = acc[1][mt][nt][r] + bj_v[nt];
                float sg = 1.f / (1.f + __expf(-yi));
                float e2 = __expf(-2.f * yj);
                float th = (1.f - e2) / (1.f + e2);
                float xv = sg * th;
                xall[r] = xv;
                s0[mt][r] += xv * xv;
            }
            uint2 pk;
            pk.x = (u32)f2bf(xall[0]) | ((u32)f2bf(xall[1]) << 16);
            pk.y = (u32)f2bf(xall[2]) | ((u32)f2bf(xall[3]) << 16);
            size_t o = (size_t)b_idx * ((size_t)HH * NN) + (size_t)h * NN
                     + (size_t)(n0 + w * 32 + mt * 16 + quad * 4);
            *reinterpret_cast<uint2*>(&xa[o]) = pk;
        }
    }
    #pragma unroll
    for (int m = 1; m <= 8; m <<= 1) {
        #pragma unroll
        for (int mt = 0; mt < 2; ++mt)
            #pragma unroll
            for (int r = 0; r < 4; ++r)
                s0[mt][r] += __shfl_xor(s0[mt][r], m, 64);
    }
    if (l15 == 0) {
        #pragma unroll
        for (int mt = 0; mt < 2; ++mt)
            #pragma unroll
            for (int r = 0; r < 4; ++r)
                atomicAdd(&normsq[m0 + w * 32 + mt * 16 + quad * 4 + r], s0[mt][r]);
    }
}

// ---------------- kernel 2: masked softmax over N per (b,s) -> out1 fp32 ----------------
__global__ __launch_bounds__(1024) void softmax_k(
    const float* __restrict__ nm, const float* __restrict__ normsq,
    float* __restrict__ out1)
{
    __shared__ float red[16];
    int bs = blockIdx.x;                 // 0..255
    int b  = bs >> 5;
    const float* src = nm + (size_t)bs * NN;
    float* dst       = out1 + (size_t)bs * NN;
    const float* ns  = normsq + (size_t)b * NN;
    int tid = threadIdx.x;
    float e[8];
    float sum = 0.f;
    #pragma unroll
    for (int i = 0; i < 8; ++i) {
        int n = i * 1024 + tid;
        float logit = src[n] * sqrtf(ns[n]);
        float v = (logit > 0.f) ? __expf(logit) : 0.f;
        e[i] = v;
        sum += v;
    }
    #pragma unroll
    for (int m = 1; m <= 32; m <<= 1) sum += __shfl_xor(sum, m, 64);
    int w = tid >> 6, lane = tid & 63;
    if (lane == 0) red[w] = sum;
    __syncthreads();
    float part = 0.f;
    #pragma unroll
    for (int j = 0; j < 16; ++j) part += red[j];
    float inv = (part > 0.f) ? (1.f / part) : 0.f;
    #pragma unroll
    for (int i = 0; i < 8; ++i) dst[i * 1024 + tid] = e[i] * inv;
}

// ---------------- kernel 3: pooling GEMM partials over 128-n chunks, 128-h halves ----------------
__global__ __launch_bounds__(256) void pooled_k(
    const u16* __restrict__ xa, const float* __restrict__ wgt,
    float* __restrict__ part)
{
    __shared__ u16 lw[32 * 136];         // [s][k] stride 136 shorts
    int bx  = blockIdx.x;                // 1024
    int b   = bx >> 7;
    int rem = bx & 127;
    int c   = rem >> 1;                  // n-chunk (128 each)
    int hg  = rem & 1;                   // h half (128 each)
    int tid = threadIdx.x, w = tid >> 6, lane = tid & 63, quad = lane >> 4, l15 = lane & 15;

    // stage weights fp32 -> bf16 (32 s x 128 n)
    {
        int s  = tid >> 3;
        int jq = (tid & 7) * 16;
        const float* src = wgt + (size_t)(b * SS + s) * NN + c * 128 + jq;
        #pragma unroll
        for (int q = 0; q < 4; ++q) {
            float4 v = *reinterpret_cast<const float4*>(src + q * 4);
            uint2 pk;
            pk.x = (u32)f2bf(v.x) | ((u32)f2bf(v.y) << 16);
            pk.y = (u32)f2bf(v.z) | ((u32)f2bf(v.w) << 16);
            *reinterpret_cast<uint2*>(&lw[s * 136 + jq + q * 4]) = pk;
        }
    }
    __syncthreads();

    f32x4 acc[2][2];
    #pragma unroll
    for (int a = 0; a < 2; ++a)
        #pragma unroll
        for (int s = 0; s < 2; ++s) acc[a][s] = (f32x4){0.f, 0.f, 0.f, 0.f};

    const u16* abase = xa + (size_t)b * ((size_t)HH * NN) + (size_t)(hg * 128) * NN + c * 128;
    #pragma unroll
    for (int kk = 0; kk < 4; ++kk) {
        short8 av[2];
        #pragma unroll
        for (int htl = 0; htl < 2; ++htl) {
            int h = w * 32 + htl * 16 + l15;
            av[htl] = *reinterpret_cast<const short8*>(abase + (size_t)h * NN + kk * 32 + quad * 8);
        }
        #pragma unroll
        for (int st = 0; st < 2; ++st) {
            int s = st * 16 + l15;
            short8 bv = *reinterpret_cast<const short8*>(&lw[s * 136 + kk * 32 + quad * 8]);
            #pragma unroll
            for (int htl = 0; htl < 2; ++htl)
                acc[htl][st] = __builtin_amdgcn_mfma_f32_16x16x32_bf16(av[htl], bv, acc[htl][st], 0, 0, 0);
        }
    }
    float* pb = part + ((size_t)(b * 64 + c) * 2 + hg) * 4096;   // [s*128 + h_local]
    #pragma unroll
    for (int htl = 0; htl < 2; ++htl) {
        #pragma unroll
        for (int st = 0; st < 2; ++st) {
            int hl = w * 32 + htl * 16 + quad * 4;
            int s  = st * 16 + l15;
            *reinterpret_cast<f32x4*>(&pb[s * 128 + hl]) = acc[htl][st];
        }
    }
}

// ---------------- kernel 4: reduce partials over 64 chunks + tanh -> out0 ----------------
__global__ __launch_bounds__(256) void reduce_tanh(const float* __restrict__ part,
                                                   float* __restrict__ out0)
{
    int gid = blockIdx.x * 256 + threadIdx.x;   // 0..65535 = b*8192 + s*256 + h
    int b = gid >> 13, r = gid & 8191;
    int s = r >> 8, h = r & 255;
    int hg = h >> 7, hl = h & 127;
    const float* p = part + ((size_t)b * 128 + hg) * 4096 + s * 128 + hl;
    float acc = 0.f;
    #pragma unroll
    for (int c = 0; c < 64; ++c) acc += p[(size_t)c * 8192];
    out0[gid] = tanhf(acc);
}

extern "C" void kernel_launch(void* const* d_in, const int* in_sizes, int n_in,
                              void* d_out, int out_size, void* d_ws, size_t ws_size,
                              hipStream_t stream) {
    const float* x  = (const float*)d_in[0];
    const float* nm = (const float*)d_in[1];
    const float* Wi = (const float*)d_in[2];
    const float* bi = (const float*)d_in[3];
    const float* Wj = (const float*)d_in[4];
    const float* bj = (const float*)d_in[5];
    float* out0 = (float*)d_out;
    float* out1 = out0 + NB * SS * HH;           // 65536

    char* ws = (char*)d_ws;
    u16*   Wb     = (u16*)ws;                                    // 327,680 B
    u16*   xa     = (u16*)(ws + 327680);                         // 33,554,432 B
    float* normsq = (float*)(ws + 327680 + 33554432);            // 262,144 B
    float* part   = (float*)(ws + 327680 + 33554432 + 262144);   // 16,777,216 B

    hipMemsetAsync(normsq, 0, NROWS * sizeof(float), stream);
    prep_w     <<<640,  256, 0, stream>>>(Wi, Wj, Wb);
    gemm_gate  <<<2048, 256, 0, stream>>>(x, Wb, bi, bj, xa, normsq);
    softmax_k  <<<256, 1024, 0, stream>>>(nm, normsq, out1);
    pooled_k   <<<1024, 256, 0, stream>>>(xa, out1, part);
    reduce_tanh<<<256,  256, 0, stream>>>(part, out0);
}

// Round 3
// 199.865 us; speedup vs baseline: 1.2702x; 1.1609x over previous
//
#include <hip/hip_runtime.h>
#include <cstdint>
#include <cstddef>

typedef unsigned short u16;
typedef unsigned int   u32;
using short8 = __attribute__((ext_vector_type(8))) short;
using f32x4  = __attribute__((ext_vector_type(4))) float;

// B=8, N=8192, H=256, A=64 (F=320), S=32
#define NB    8
#define NN    8192
#define HH    256
#define FF    320
#define SS    32
#define NROWS 65536
#define NCH   32            // pooling K-split chunks (256 n each)

__device__ __forceinline__ u16 f2bf(float f) {
    union { float f; u32 u; } v; v.f = f;
    u32 r = v.u + 0x7fffu + ((v.u >> 16) & 1u);   // RNE
    return (u16)(r >> 16);
}
__device__ __forceinline__ u32 pk2(float a, float b) {
    return (u32)f2bf(a) | ((u32)f2bf(b) << 16);
}
__device__ __forceinline__ short8 pack8(float4 a, float4 b) {
    union { u32 u[4]; short8 s; } r;
    r.u[0] = pk2(a.x, a.y); r.u[1] = pk2(a.z, a.w);
    r.u[2] = pk2(b.x, b.y); r.u[3] = pk2(b.z, b.w);
    return r.s;
}

// ---------------- prep: cast Wi,Wj to bf16 (concat) + zero normsq ----------------
__global__ __launch_bounds__(256) void prep_w(const float* __restrict__ Wi,
                                              const float* __restrict__ Wj,
                                              u16* __restrict__ Wb,
                                              float* __restrict__ normsq) {
    int idx = blockIdx.x * 256 + threadIdx.x;       // 0..163839
    float v = (idx < 81920) ? Wi[idx] : Wj[idx - 81920];
    Wb[idx] = f2bf(v);
    if (idx < NROWS) normsq[idx] = 0.f;
}

// ---------------- kernel 1: gated features + norm^2 ----------------
// Block: 512 thr (8 waves), 256 rows x 128 cols (2 mats x 64 h). B full-K resident in LDS
// (80 KB, one barrier); A loaded direct global->VGPR in MFMA fragment layout, cast in-reg.
// Grid 1024: xcd-swizzled so the 4 h-tiles of one m-tile share an XCD (x read once per L2).
__global__ __launch_bounds__(512, 4) void gemm_gate(
    const float* __restrict__ x, const u16* __restrict__ Wb,
    const float* __restrict__ bi, const float* __restrict__ bj,
    u16* __restrict__ xa, float* __restrict__ normsq)
{
    __shared__ u16 lB[5 * 8192];      // [kt][row 0..127][swizzled k-slot*8], 81920 B

    const int bx   = blockIdx.x;
    const int xcd  = bx & 7;
    const int ht   = (bx >> 3) & 3;
    const int slot = bx >> 5;         // 0..31
    const int mb   = xcd + slot * 8;  // 0..255
    const int m0   = mb * 256;
    const int h0   = ht * 64;
    const int b_idx = m0 >> 13;
    const int n0    = m0 & 8191;

    const int tid  = threadIdx.x;
    const int w    = tid >> 6;        // 0..7
    const int lane = tid & 63;
    const int quad = lane >> 4;
    const int l15  = lane & 15;

    // ---- one-time B load: 5 kt x 2 issues per wave (16 issues of 1 KB per kt) ----
    {
        const int rsub = lane >> 3;                 // 0..7
        const int kg   = (lane & 7) ^ rsub;         // XOR swizzle
        #pragma unroll
        for (int kt = 0; kt < 5; ++kt) {
            #pragma unroll
            for (int j = 0; j < 2; ++j) {
                int sl  = w * 2 + j;                // 0..15
                int row = sl * 8 + rsub;            // 0..127
                int mat = row >> 6, hl = row & 63;
                const u16* gsrc = Wb + mat * 81920 + (size_t)(h0 + hl) * FF + kt * 64 + kg * 8;
                u16* ldst = &lB[kt * 8192 + sl * 512];
                __builtin_amdgcn_global_load_lds(
                    (const __attribute__((address_space(1))) void*)gsrc,
                    (__attribute__((address_space(3))) void*)ldst, 16, 0, 0);
            }
        }
    }

    // ---- A fragment addressing: row = m0 + w*32 + mt*16 + l15, k = ks*32 + quad*8 ----
    const float* xb = x + (size_t)(m0 + w * 32 + l15) * FF + quad * 8;

    f32x4 acc[8][2];                  // [matnt(col/16)][mt]
    #pragma unroll
    for (int a = 0; a < 8; ++a)
        #pragma unroll
        for (int m = 0; m < 2; ++m) acc[a][m] = (f32x4){0.f, 0.f, 0.f, 0.f};

    float4 pre[2][2][2];              // [buf][mt][half]
    #pragma unroll
    for (int mt = 0; mt < 2; ++mt) {
        pre[0][mt][0] = *reinterpret_cast<const float4*>(xb + mt * 16 * FF);
        pre[0][mt][1] = *reinterpret_cast<const float4*>(xb + mt * 16 * FF + 4);
    }

    __syncthreads();                  // B resident + pre[0] ready

    #pragma unroll
    for (int kt = 0; kt < 5; ++kt) {
        #pragma unroll
        for (int kk = 0; kk < 2; ++kk) {
            const int ks  = kt * 2 + kk;
            const int cur = ks & 1, nxt = cur ^ 1;
            if (ks < 9) {
                const int f = (ks + 1) * 32;
                #pragma unroll
                for (int mt = 0; mt < 2; ++mt) {
                    pre[nxt][mt][0] = *reinterpret_cast<const float4*>(xb + mt * 16 * FF + f);
                    pre[nxt][mt][1] = *reinterpret_cast<const float4*>(xb + mt * 16 * FF + f + 4);
                }
            }
            short8 af[2];
            #pragma unroll
            for (int mt = 0; mt < 2; ++mt)
                af[mt] = pack8(pre[cur][mt][0], pre[cur][mt][1]);
            #pragma unroll
            for (int mn = 0; mn < 8; ++mn) {
                int c = mn * 16 + l15;
                short8 bv = *reinterpret_cast<const short8*>(
                    &lB[kt * 8192 + c * 64 + (((kk * 4 + quad) ^ (c & 7)) << 3)]);
                acc[mn][0] = __builtin_amdgcn_mfma_f32_16x16x32_bf16(af[0], bv, acc[mn][0], 0, 0, 0);
                acc[mn][1] = __builtin_amdgcn_mfma_f32_16x16x32_bf16(af[1], bv, acc[mn][1], 0, 0, 0);
            }
        }
    }

    // ---- epilogue: gate, store xa [b][h][n], norm^2 ----
    float s0[2][4];
    #pragma unroll
    for (int mt = 0; mt < 2; ++mt)
        #pragma unroll
        for (int r = 0; r < 4; ++r) s0[mt][r] = 0.f;

    #pragma unroll
    for (int hq = 0; hq < 4; ++hq) {
        int h = h0 + hq * 16 + l15;
        float bi_v = bi[h], bj_v = bj[h];
        #pragma unroll
        for (int mt = 0; mt < 2; ++mt) {
            float xall[4];
            #pragma unroll
            for (int r = 0; r < 4; ++r) {
                float yi = acc[hq][mt][r] + bi_v;
                float yj = acc[hq + 4][mt][r] + bj_v;
                float sg = 1.f / (1.f + __expf(-yi));
                float e2 = __expf(-2.f * yj);
                float th = (1.f - e2) / (1.f + e2);
                float xv = sg * th;
                xall[r] = xv;
                s0[mt][r] += xv * xv;
            }
            uint2 pk;
            pk.x = pk2(xall[0], xall[1]);
            pk.y = pk2(xall[2], xall[3]);
            size_t o = (size_t)b_idx * ((size_t)HH * NN) + (size_t)h * NN
                     + (size_t)(n0 + w * 32 + mt * 16 + quad * 4);
            *reinterpret_cast<uint2*>(&xa[o]) = pk;
        }
    }
    #pragma unroll
    for (int m = 1; m <= 8; m <<= 1) {
        #pragma unroll
        for (int mt = 0; mt < 2; ++mt)
            #pragma unroll
            for (int r = 0; r < 4; ++r)
                s0[mt][r] += __shfl_xor(s0[mt][r], m, 64);
    }
    if (l15 == 0) {
        #pragma unroll
        for (int mt = 0; mt < 2; ++mt)
            #pragma unroll
            for (int r = 0; r < 4; ++r)
                atomicAdd(&normsq[m0 + w * 32 + mt * 16 + quad * 4 + r], s0[mt][r]);
    }
}

// ---------------- kernel 2: masked softmax over N per (b,s) -> out1 fp32 ----------------
__global__ __launch_bounds__(1024) void softmax_k(
    const float* __restrict__ nm, const float* __restrict__ normsq,
    float* __restrict__ out1)
{
    __shared__ float red[16];
    int bs = blockIdx.x;                 // 0..255
    int b  = bs >> 5;
    const float* src = nm + (size_t)bs * NN;
    float* dst       = out1 + (size_t)bs * NN;
    const float* ns  = normsq + (size_t)b * NN;
    int tid = threadIdx.x;
    float e[8];
    float sum = 0.f;
    #pragma unroll
    for (int i = 0; i < 8; ++i) {
        int n = i * 1024 + tid;
        float logit = src[n] * sqrtf(ns[n]);
        float v = (logit > 0.f) ? __expf(logit) : 0.f;
        e[i] = v;
        sum += v;
    }
    #pragma unroll
    for (int m = 1; m <= 32; m <<= 1) sum += __shfl_xor(sum, m, 64);
    int w = tid >> 6, lane = tid & 63;
    if (lane == 0) red[w] = sum;
    __syncthreads();
    float part = 0.f;
    #pragma unroll
    for (int j = 0; j < 16; ++j) part += red[j];
    float inv = (part > 0.f) ? (1.f / part) : 0.f;
    #pragma unroll
    for (int i = 0; i < 8; ++i) dst[i * 1024 + tid] = e[i] * inv;
}

// ---------------- kernel 3: pooling GEMM partials over 256-n chunks ----------------
__global__ __launch_bounds__(256) void pooled_k(
    const u16* __restrict__ xa, const float* __restrict__ wgt,
    float* __restrict__ part)
{
    __shared__ u16 lw[32 * 264];         // [s][k] stride 264 shorts (528 B)
    int bx = blockIdx.x;                 // 256
    int b  = bx >> 5, c = bx & 31;
    int n0 = c * 256;
    int tid = threadIdx.x, w = tid >> 6, lane = tid & 63, quad = lane >> 4, l15 = lane & 15;

    // stage weights fp32 -> bf16 (32 s x 256 n); thread: s = tid>>3, n-sub = (tid&7)*32
    {
        int s  = tid >> 3;
        int nb = (tid & 7) * 32;
        const float* src = wgt + (size_t)(b * SS + s) * NN + n0 + nb;
        #pragma unroll
        for (int q = 0; q < 8; ++q) {
            float4 v = *reinterpret_cast<const float4*>(src + q * 4);
            uint2 pk;
            pk.x = pk2(v.x, v.y);
            pk.y = pk2(v.z, v.w);
            *reinterpret_cast<uint2*>(&lw[s * 264 + nb + q * 4]) = pk;
        }
    }
    __syncthreads();

    f32x4 acc[4][2];
    #pragma unroll
    for (int a = 0; a < 4; ++a)
        #pragma unroll
        for (int s = 0; s < 2; ++s) acc[a][s] = (f32x4){0.f, 0.f, 0.f, 0.f};

    const u16* ab = xa + (size_t)b * ((size_t)HH * NN) + n0;
    #pragma unroll
    for (int ks = 0; ks < 8; ++ks) {
        short8 av[4];
        #pragma unroll
        for (int htl = 0; htl < 4; ++htl) {
            int h = w * 64 + htl * 16 + l15;
            av[htl] = *reinterpret_cast<const short8*>(ab + (size_t)h * NN + ks * 32 + quad * 8);
        }
        #pragma unroll
        for (int st = 0; st < 2; ++st) {
            int s = st * 16 + l15;
            short8 bv = *reinterpret_cast<const short8*>(&lw[s * 264 + ks * 32 + quad * 8]);
            #pragma unroll
            for (int htl = 0; htl < 4; ++htl)
                acc[htl][st] = __builtin_amdgcn_mfma_f32_16x16x32_bf16(av[htl], bv, acc[htl][st], 0, 0, 0);
        }
    }
    float* pb = part + (size_t)(b * NCH + c) * 8192;   // [s*256 + h]
    #pragma unroll
    for (int htl = 0; htl < 4; ++htl) {
        #pragma unroll
        for (int st = 0; st < 2; ++st) {
            int h = w * 64 + htl * 16 + quad * 4;
            int s = st * 16 + l15;
            *reinterpret_cast<f32x4*>(&pb[s * 256 + h]) = acc[htl][st];
        }
    }
}

// ---------------- kernel 4: reduce partials over 32 chunks + tanh -> out0 ----------------
__global__ __launch_bounds__(256) void reduce_tanh(const float* __restrict__ part,
                                                   float* __restrict__ out0)
{
    int gid = blockIdx.x * 256 + threadIdx.x;   // 0..65535 = b*8192 + s*256 + h
    int b = gid >> 13, r = gid & 8191;
    const float* p = part + (size_t)b * NCH * 8192 + r;
    float s = 0.f;
    #pragma unroll
    for (int c = 0; c < NCH; ++c) s += p[(size_t)c * 8192];
    out0[gid] = tanhf(s);
}

extern "C" void kernel_launch(void* const* d_in, const int* in_sizes, int n_in,
                              void* d_out, int out_size, void* d_ws, size_t ws_size,
                              hipStream_t stream) {
    const float* x  = (const float*)d_in[0];
    const float* nm = (const float*)d_in[1];
    const float* Wi = (const float*)d_in[2];
    const float* bi = (const float*)d_in[3];
    const float* Wj = (const float*)d_in[4];
    const float* bj = (const float*)d_in[5];
    float* out0 = (float*)d_out;
    float* out1 = out0 + NB * SS * HH;           // 65536

    char* ws = (char*)d_ws;
    u16*   Wb     = (u16*)ws;                                    // 327,680 B
    u16*   xa     = (u16*)(ws + 327680);                         // 33,554,432 B
    float* normsq = (float*)(ws + 327680 + 33554432);            // 262,144 B
    float* part   = (float*)(ws + 327680 + 33554432 + 262144);   // 8,388,608 B

    prep_w     <<<640,  256, 0, stream>>>(Wi, Wj, Wb, normsq);
    gemm_gate  <<<1024, 512, 0, stream>>>(x, Wb, bi, bj, xa, normsq);
    softmax_k  <<<256, 1024, 0, stream>>>(nm, normsq, out1);
    pooled_k   <<<256,  256, 0, stream>>>(xa, out1, part);
    reduce_tanh<<<256,  256, 0, stream>>>(part, out0);
}